// Round 13
// baseline (305.345 us; speedup 1.0000x reference)
//
#include <hip/hip_runtime.h>
#include <hip/hip_bf16.h>

// ParallelNCA on MFMA: 64 grouped MLPs (144->128->16) over 3x3 perception.
// Round 13 = round 12 with NP 128 -> 64: LDS 39.4 -> 19.5 KB => 8 blocks/CU
// (occupancy 40% -> ~80%) for latency hiding across barrier-phased blocks.
// Two-level (m-chunk x group) dispatch tiling kept (r12: FETCH 245->149 MB).
// prep_border + prep_w merged into one aux kernel.

typedef __attribute__((ext_vector_type(8))) short short8;   // 8 bf16 frag
typedef __attribute__((ext_vector_type(4))) float f32x4;    // MFMA acc

constexpr int Bn  = 16;
constexpr int Mn  = 64;
constexpr int Cn  = 16;
constexpr int Hd  = 128;
constexpr int K9  = 144;
constexpr int MCn = 1024;
constexpr int NP  = 64;         // pixels per block (2 image rows)
constexpr int PT_STRIDE = 304;  // bytes/pixel row of Pt (76 words)
constexpr int HT_STRIDE = 272;  // bytes/pixel row of Ht
constexpr int NT  = 256;

// pixel-major padded bf16 x: [b][h' 0..33][w' 0..33][mc 0..1023]
constexpr size_t XPM_SLABS = 34 * 34;                       // per b
constexpr size_t XPM_B     = XPM_SLABS * MCn;               // ushorts per b
constexpr size_t XPM_BYTES = (size_t)Bn * XPM_B * 2;        // 37,879,808
constexpr size_t W1_ELEMS  = (size_t)Mn * Hd * K9;          // 1,179,648
constexpr size_t W2_ELEMS  = (size_t)Mn * Cn * Hd;          // 131,072
constexpr size_t WS_NEED   = XPM_BYTES + 2 * (W1_ELEMS + W2_ELEMS);

constexpr int NB_BORDER = Bn * 132;                         // 2112 aux blocks
constexpr int NB_W      = (int)((W1_ELEMS + W2_ELEMS) / 4 / 256);  // 1280

__device__ __forceinline__ ushort f2bf(float f) {
    return __bfloat16_as_ushort(__float2bfloat16(f));
}
__device__ __forceinline__ float bf2f(ushort u) {
    union { uint i; float f; } v; v.i = (uint)u << 16; return v.f;
}

// ---------------------------------------------------------------------------
// prep: x [b][mc][32][32] f32 -> xpm [b][h+1][w+1][mc] bf16 (interior only)
// ---------------------------------------------------------------------------
__global__ __launch_bounds__(256)
void prep_xpm(const float* __restrict__ x, ushort* __restrict__ xpm)
{
    const int bid = blockIdx.x;
    const int b  = bid >> 7;
    const int h  = (bid >> 2) & 31;
    const int ck = bid & 3;
    const int tid = threadIdx.x;

    __shared__ ushort T[256][36];   // [mc_local][w], padded

    const int mc = ck * 256 + tid;
    const float* src = x + (((size_t)b * MCn + mc) * 32 + h) * 32;
    #pragma unroll
    for (int j = 0; j < 8; ++j) {
        const float4 f = *(const float4*)(src + 4 * j);
        uint2 pk;
        pk.x = (uint)f2bf(f.x) | ((uint)f2bf(f.y) << 16);
        pk.y = (uint)f2bf(f.z) | ((uint)f2bf(f.w) << 16);
        *(uint2*)&T[tid][4 * j] = pk;
    }
    __syncthreads();

    // write: 4 reps x 256 threads cover 256 mc x 32 w (coalesced 16B chunks)
    ushort* const dstb = xpm + (size_t)b * XPM_B + ((size_t)(h + 1) * 34) * MCn
                       + ck * 256;
    #pragma unroll
    for (int rep = 0; rep < 4; ++rep) {
        const int q8 = tid & 31;               // mc_local group (8 channels)
        const int w  = (tid >> 5) + 8 * rep;   // pixel column
        ushort tmp[8];
        #pragma unroll
        for (int k2 = 0; k2 < 8; ++k2) tmp[k2] = T[8 * q8 + k2][w];
        uint4 v;
        v.x = (uint)tmp[0] | ((uint)tmp[1] << 16);
        v.y = (uint)tmp[2] | ((uint)tmp[3] << 16);
        v.z = (uint)tmp[4] | ((uint)tmp[5] << 16);
        v.w = (uint)tmp[6] | ((uint)tmp[7] << 16);
        *(uint4*)(dstb + (size_t)(w + 1) * MCn + 8 * q8) = v;
    }
}

// aux: border zero-fill (blocks [0, NB_BORDER)) + weight cvt (rest)
__global__ __launch_bounds__(256)
void prep_aux(const float* __restrict__ w1, const float* __restrict__ w2,
              ushort* __restrict__ w1bf, ushort* __restrict__ w2bf,
              ushort* __restrict__ xpm)
{
    const int bid = blockIdx.x;
    const int tid = threadIdx.x;
    if (bid < NB_BORDER) {
        const int b   = bid / 132;
        const int pos = bid % 132;
        int hh, ww;
        if      (pos < 34)  { hh = 0;              ww = pos;        }
        else if (pos < 68)  { hh = 33;             ww = pos - 34;   }
        else if (pos < 100) { hh = pos - 68 + 1;   ww = 0;          }
        else                { hh = pos - 100 + 1;  ww = 33;         }
        ushort* dst = xpm + (size_t)b * XPM_B + ((size_t)hh * 34 + ww) * MCn
                    + tid * 4;
        *(uint2*)dst = (uint2){0, 0};
    } else {
        const size_t i = ((size_t)(bid - NB_BORDER) * 256 + tid) * 4;
        const float* src; ushort* dst; size_t e;
        if (i < W1_ELEMS) { src = w1; dst = w1bf; e = i; }
        else              { src = w2; dst = w2bf; e = i - W1_ELEMS; }
        const float4 f = *(const float4*)(src + e);
        uint2 pk;
        pk.x = (uint)f2bf(f.x) | ((uint)f2bf(f.y) << 16);
        pk.y = (uint)f2bf(f.z) | ((uint)f2bf(f.w) << 16);
        *(uint2*)(dst + e) = pk;
    }
}

// ---------------------------------------------------------------------------
// main kernel (pixel-major bf16 source; never touches f32 x). NP=64.
// ---------------------------------------------------------------------------
__global__ __launch_bounds__(NT, 8)
void nca_mfma_pm(const ushort* __restrict__ xpm,
                 const ushort* __restrict__ w1bf, const float* __restrict__ b1,
                 const ushort* __restrict__ w2bf, const float* __restrict__ b2,
                 float* __restrict__ out)
{
    // union: Pt[64][304B] bf16 perception; then Ht[64][272B]; then dxT f32.
    __shared__ __align__(16) char U[NP * PT_STRIDE + 16];   // 19472 B
    char* const PtL = U;
    char* const HtL = U;

    const int tid  = threadIdx.x;
    const int lane = tid & 63;
    const int wid  = tid >> 6;      // wave 0..3
    const int lr   = lane & 15;     // MFMA row/col lane index
    const int lk   = lane >> 4;     // MFMA k-group 0..3

    // two-level dispatch tiling per XCD: grid 16384.
    //   j = bid>>3: mlo = j&31 (fast), glo = (j>>5)&31 (mid), mch = j>>10 (slow)
    const int bid = blockIdx.x;
    const int xcd = bid & 7;
    const int j   = bid >> 3;               // 0..2047
    const int mlo = j & 31;
    const int glo = (j >> 5) & 31;
    const int mch = j >> 10;                // 0..1
    const int m   = mch * 32 + mlo;         // model 0..63
    const int g   = glo * 8 + xcd;          // pixel group 0..255
    const int b   = g >> 4;                 // batch 0..15
    const int p0  = (g & 15) * NP;          // pixel base within image

    const ushort* const xpb = xpm + (size_t)b * XPM_B;

    // zero k-pad columns [288,304) of each row + 16B guard after row 63
    if (tid <= NP) {
        char* z = PtL + tid * PT_STRIDE + (tid < NP ? 288 : 0);
        *(int4*)z = (int4){0, 0, 0, 0};
    }

    // ---------- w1 bf16 A-frags ----------
    short8 a1[2][5];
    #pragma unroll
    for (int rt = 0; rt < 2; ++rt) {
        const int row = wid * 32 + rt * 16 + lr;
        const ushort* wr = w1bf + (m * Hd + row) * K9;
        #pragma unroll
        for (int ks = 0; ks < 5; ++ks) {
            const int k0 = ks * 32 + lk * 8;
            a1[rt][ks] = (k0 < K9) ? *(const short8*)(wr + k0)
                                   : (short8){0,0,0,0,0,0,0,0};
        }
    }
    // ---------- w2 bf16 A-frags ----------
    short8 a2[4];
    #pragma unroll
    for (int ks = 0; ks < 4; ++ks)
        a2[ks] = *(const short8*)(w2bf + (m * Cn + lr) * Hd + ks * 32 + lk * 8);

    // ---------- gather: xpm -> Pt (two contiguous runs per pixel row) ----------
    // 128 active threads: p = tid>>1 (64 px), c0c = (tid&1)*72. 9 uint4 each.
    if (tid < 128) {
        const unsigned long long TAB = 0xA62918405ull;  // (dr+1)|((dc+1)<<2)
        const int ch0  = m * K9;
        const int s0g  = ch0 >> 10;
        const int mc0  = ch0 & 1023;
        const int len0 = min(K9, 1024 - mc0);
        const uint nib0 = (uint)(TAB >> (4 * s0g)) & 15u;
        const uint nib1 = (uint)(TAB >> (4 * (s0g + 1))) & 15u;
        const int dr0 = (int)(nib0 & 3u) - 1, dc0 = (int)(nib0 >> 2) - 1;
        const int dr1 = (int)(nib1 & 3u) - 1, dc1 = (int)(nib1 >> 2) - 1;

        const int p   = tid >> 1;
        const int c0c = (tid & 1) * 72;         // half-row: ch [c0c, c0c+72)
        const int gp  = p0 + p;
        const int h   = gp >> 5, w = gp & 31;
        const ushort* src0 = xpb + ((h + dr0 + 1) * 34 + (w + dc0 + 1)) * MCn + mc0;
        const ushort* src1 = xpb + ((h + dr1 + 1) * 34 + (w + dc1 + 1)) * MCn;
        char* const dstb = PtL + p * PT_STRIDE + c0c * 2;

        #pragma unroll
        for (int i = 0; i < 9; ++i) {
            const int ko = c0c + 8 * i;         // mult of 8 ch = 16B units
            const ushort* s = (ko < len0) ? (src0 + ko) : (src1 + (ko - len0));
            *(uint4*)(dstb + 16 * i) = *(const uint4*)s;
        }
    }
    __syncthreads();

    // ---------- GEMM1: hdn = w1 @ P, 128x64x160 ----------
    f32x4 acc[2][4];
    #pragma unroll
    for (int i = 0; i < 2; ++i)
        #pragma unroll
        for (int jj = 0; jj < 4; ++jj) acc[i][jj] = (f32x4){0.f, 0.f, 0.f, 0.f};

    #pragma unroll
    for (int ct = 0; ct < 4; ++ct) {
        const int p = ct * 16 + lr;
        const char* base = PtL + p * PT_STRIDE + lk * 16;
        short8 bfrag[5];
        #pragma unroll
        for (int ks = 0; ks < 5; ++ks)
            bfrag[ks] = *(const short8*)(base + ks * 64);
        #pragma unroll
        for (int ks = 0; ks < 5; ++ks) {
            acc[0][ct] = __builtin_amdgcn_mfma_f32_16x16x32_bf16(a1[0][ks], bfrag[ks], acc[0][ct], 0, 0, 0);
            acc[1][ct] = __builtin_amdgcn_mfma_f32_16x16x32_bf16(a1[1][ks], bfrag[ks], acc[1][ct], 0, 0, 0);
        }
    }
    __syncthreads();   // Pt reads done -> reuse U as Ht

    // ---------- bias+relu -> Ht[p][hd] bf16 ----------
    #pragma unroll
    for (int rt = 0; rt < 2; ++rt) {
        const int hd0 = wid * 32 + rt * 16 + lk * 4;   // C/D row = (lane>>4)*4 + reg
        const float4 bs = *(const float4*)(b1 + m * Hd + hd0);
        #pragma unroll
        for (int ct = 0; ct < 4; ++ct) {
            const int p = ct * 16 + lr;                // C/D col = lane&15
            const f32x4 v = acc[rt][ct];
            uint2 pk;
            pk.x = (uint)f2bf(fmaxf(v[0] + bs.x, 0.f)) |
                   ((uint)f2bf(fmaxf(v[1] + bs.y, 0.f)) << 16);
            pk.y = (uint)f2bf(fmaxf(v[2] + bs.z, 0.f)) |
                   ((uint)f2bf(fmaxf(v[3] + bs.w, 0.f)) << 16);
            *(uint2*)(HtL + p * HT_STRIDE + hd0 * 2) = pk;
        }
    }
    __syncthreads();

    // ---------- GEMM2: dx = w2 @ hdn, 16x64x128 (wave wid -> col-tile wid) ----
    f32x4 acc2;
    {
        const int p  = wid * 16 + lr;
        const char* base = HtL + p * HT_STRIDE + lk * 16;
        short8 bb[4];
        #pragma unroll
        for (int ks = 0; ks < 4; ++ks)
            bb[ks] = *(const short8*)(base + ks * 64);
        f32x4 a = (f32x4){0.f, 0.f, 0.f, 0.f};
        #pragma unroll
        for (int ks = 0; ks < 4; ++ks)
            a = __builtin_amdgcn_mfma_f32_16x16x32_bf16(a2[ks], bb[ks], a, 0, 0, 0);
        acc2 = a;
    }
    __syncthreads();   // Ht reads done -> reuse U as dxT

    // ---------- epilogue: residual(bf16 xpm) + bias -> dxT -> 256B out writes ---
    const float4 b2v = *(const float4*)(b2 + m * Cn + lk * 4);
    float (*dxT)[NP + 4] = (float(*)[NP + 4])U;   // 16 x 68 f32
    {
        const float bsv[4] = {b2v.x, b2v.y, b2v.z, b2v.w};
        const int px = wid * 16 + lr;
        const int gp = p0 + px;
        const int h  = gp >> 5, w = gp & 31;
        const ushort* res = xpb + ((h + 1) * 34 + (w + 1)) * MCn + m * Cn + lk * 4;
        #pragma unroll
        for (int rr2 = 0; rr2 < 4; ++rr2)
            dxT[lk * 4 + rr2][px] = acc2[rr2] + bsv[rr2] + bf2f(res[rr2]);
    }
    __syncthreads();
    {
        const int c = tid >> 4, iq = tid & 15;
        const int px0 = 4 * iq;
        const float4 d0 = *(const float4*)&dxT[c][px0];
        const size_t idx = ((size_t)(b * MCn + m * Cn + c)) * 1024 + p0 + px0;
        *(float4*)(out + idx) = d0;
    }
}

// ---------------------------------------------------------------------------
// fallback (f32-direct, round 6, NP=128): used when ws_size < WS_NEED
// ---------------------------------------------------------------------------
__global__ __launch_bounds__(NT, 4)
void nca_mfma_f32src(const float* __restrict__ x,  const float* __restrict__ w1,
                     const float* __restrict__ b1, const float* __restrict__ w2,
                     const float* __restrict__ b2, float* __restrict__ out)
{
    __shared__ __align__(16) char U[128 * PT_STRIDE + 16];
    char* const PtL = U;
    char* const HtL = U;

    const int tid  = threadIdx.x;
    const int lane = tid & 63;
    const int wid  = tid >> 6;
    const int lr   = lane & 15;
    const int lk   = lane >> 4;

    const int bid = blockIdx.x;
    const int xcd = bid & 7;
    const int jb  = bid >> 3;
    const int m   = jb & 63;
    const int g   = (jb >> 6) * 8 + xcd;
    const int b   = g >> 3;
    const int p0  = (g & 7) * 128;

    if (tid <= 128) {
        char* z = PtL + tid * PT_STRIDE + (tid < 128 ? 288 : 0);
        *(int4*)z = (int4){0, 0, 0, 0};
    }

    short8 a1[2][5];
    #pragma unroll
    for (int rt = 0; rt < 2; ++rt) {
        const int row = wid * 32 + rt * 16 + lr;
        const float* wr = w1 + (m * Hd + row) * K9;
        #pragma unroll
        for (int ks = 0; ks < 5; ++ks) {
            const int k0 = ks * 32 + lk * 8;
            short8 t;
            if (k0 < K9) {
                const float4 f0 = *(const float4*)(wr + k0);
                const float4 f1 = *(const float4*)(wr + k0 + 4);
                t[0] = (short)f2bf(f0.x); t[1] = (short)f2bf(f0.y);
                t[2] = (short)f2bf(f0.z); t[3] = (short)f2bf(f0.w);
                t[4] = (short)f2bf(f1.x); t[5] = (short)f2bf(f1.y);
                t[6] = (short)f2bf(f1.z); t[7] = (short)f2bf(f1.w);
            } else t = (short8){0,0,0,0,0,0,0,0};
            a1[rt][ks] = t;
        }
    }
    short8 a2[4];
    #pragma unroll
    for (int ks = 0; ks < 4; ++ks) {
        const float* wr = w2 + (m * Cn + lr) * Hd + ks * 32 + lk * 8;
        const float4 f0 = *(const float4*)(wr);
        const float4 f1 = *(const float4*)(wr + 4);
        short8 t;
        t[0] = (short)f2bf(f0.x); t[1] = (short)f2bf(f0.y);
        t[2] = (short)f2bf(f0.z); t[3] = (short)f2bf(f0.w);
        t[4] = (short)f2bf(f1.x); t[5] = (short)f2bf(f1.y);
        t[6] = (short)f2bf(f1.z); t[7] = (short)f2bf(f1.w);
        a2[ks] = t;
    }
    {
        const int s     = tid & 7;
        const int kpl   = (tid >> 3) & 7;
        const int r     = tid >> 6;
        const int rbase = (g & 7) * 4 + r;
        const float* xb = x + (size_t)b * (MCn * 1024);
        const unsigned long long TAB = 0xA62918405ull;
        #pragma unroll
        for (int it = 0; it < 9; ++it) {
            const int kp = it * 8 + kpl;
            float4 hv[2];
            #pragma unroll
            for (int half = 0; half < 2; ++half) {
                const int ch = m * K9 + kp * 2 + half;
                const int sh = ch >> 10;
                const int mc = ch & 1023;
                const uint nib = (uint)(TAB >> (4 * sh)) & 15u;
                const int dr = (int)(nib & 3u) - 1;
                const int dc = (int)(nib >> 2) - 1;
                const int row = rbase + dr;
                const int wb  = 4 * s + dc;
                const int wc  = min(max(wb, 0), 28);
                float4 f = {0.f, 0.f, 0.f, 0.f};
                if ((unsigned)row < 32u)
                    f = *(const float4*)(xb + (mc * 32 + row) * 32 + wc);
                if (wb < 0)       { f.w = f.z; f.z = f.y; f.y = f.x; f.x = 0.f; }
                else if (wb > 28) { f.x = f.y; f.y = f.z; f.z = f.w; f.w = 0.f; }
                hv[half] = f;
            }
            char* dst = PtL + (r * 32 + 4 * s) * PT_STRIDE + kp * 4;
            *(uint*)(dst)                 = (uint)f2bf(hv[0].x) | ((uint)f2bf(hv[1].x) << 16);
            *(uint*)(dst + PT_STRIDE)     = (uint)f2bf(hv[0].y) | ((uint)f2bf(hv[1].y) << 16);
            *(uint*)(dst + 2 * PT_STRIDE) = (uint)f2bf(hv[0].z) | ((uint)f2bf(hv[1].z) << 16);
            *(uint*)(dst + 3 * PT_STRIDE) = (uint)f2bf(hv[0].w) | ((uint)f2bf(hv[1].w) << 16);
        }
    }
    __syncthreads();

    f32x4 acc[2][8];
    #pragma unroll
    for (int i = 0; i < 2; ++i)
        #pragma unroll
        for (int jj = 0; jj < 8; ++jj) acc[i][jj] = (f32x4){0.f, 0.f, 0.f, 0.f};
    #pragma unroll
    for (int ct = 0; ct < 8; ++ct) {
        const int p = ct * 16 + lr;
        const char* base = PtL + p * PT_STRIDE + lk * 16;
        short8 bfrag[5];
        #pragma unroll
        for (int ks = 0; ks < 5; ++ks)
            bfrag[ks] = *(const short8*)(base + ks * 64);
        #pragma unroll
        for (int ks = 0; ks < 5; ++ks) {
            acc[0][ct] = __builtin_amdgcn_mfma_f32_16x16x32_bf16(a1[0][ks], bfrag[ks], acc[0][ct], 0, 0, 0);
            acc[1][ct] = __builtin_amdgcn_mfma_f32_16x16x32_bf16(a1[1][ks], bfrag[ks], acc[1][ct], 0, 0, 0);
        }
    }
    __syncthreads();
    #pragma unroll
    for (int rt = 0; rt < 2; ++rt) {
        const int hd0 = wid * 32 + rt * 16 + lk * 4;
        const float4 bs = *(const float4*)(b1 + m * Hd + hd0);
        #pragma unroll
        for (int ct = 0; ct < 8; ++ct) {
            const int p = ct * 16 + lr;
            const f32x4 v = acc[rt][ct];
            uint2 pk;
            pk.x = (uint)f2bf(fmaxf(v[0] + bs.x, 0.f)) |
                   ((uint)f2bf(fmaxf(v[1] + bs.y, 0.f)) << 16);
            pk.y = (uint)f2bf(fmaxf(v[2] + bs.z, 0.f)) |
                   ((uint)f2bf(fmaxf(v[3] + bs.w, 0.f)) << 16);
            *(uint2*)(HtL + p * HT_STRIDE + hd0 * 2) = pk;
        }
    }
    __syncthreads();
    f32x4 acc2[2];
    #pragma unroll
    for (int jj = 0; jj < 2; ++jj) {
        const int ct = wid * 2 + jj;
        const int p  = ct * 16 + lr;
        const char* base = HtL + p * HT_STRIDE + lk * 16;
        short8 bb[4];
        #pragma unroll
        for (int ks = 0; ks < 4; ++ks)
            bb[ks] = *(const short8*)(base + ks * 64);
        f32x4 a = (f32x4){0.f, 0.f, 0.f, 0.f};
        #pragma unroll
        for (int ks = 0; ks < 4; ++ks)
            a = __builtin_amdgcn_mfma_f32_16x16x32_bf16(a2[ks], bb[ks], a, 0, 0, 0);
        acc2[jj] = a;
    }
    const float4 b2v = *(const float4*)(b2 + m * Cn + lk * 4);
    const float bsv[4] = {b2v.x, b2v.y, b2v.z, b2v.w};
    #pragma unroll
    for (int jj = 0; jj < 2; ++jj) {
        const int ct = wid * 2 + jj;
        const int gp = p0 + ct * 16 + lr;
        #pragma unroll
        for (int r = 0; r < 4; ++r) {
            const int c   = lk * 4 + r;
            const size_t idx = ((size_t)(b * MCn + m * Cn + c)) * 1024 + gp;
            out[idx] = x[idx] + acc2[jj][r] + bsv[r];
        }
    }
}

extern "C" void kernel_launch(void* const* d_in, const int* in_sizes, int n_in,
                              void* d_out, int out_size, void* d_ws, size_t ws_size,
                              hipStream_t stream)
{
    const float* x  = (const float*)d_in[0];
    const float* w1 = (const float*)d_in[1];
    const float* b1 = (const float*)d_in[2];
    const float* w2 = (const float*)d_in[3];
    const float* b2 = (const float*)d_in[4];
    float* out = (float*)d_out;

    if (ws_size >= WS_NEED) {
        ushort* xpm  = (ushort*)d_ws;
        ushort* w1bf = (ushort*)((char*)d_ws + XPM_BYTES);
        ushort* w2bf = w1bf + W1_ELEMS;
        prep_xpm<<<Bn * 32 * 4, 256, 0, stream>>>(x, xpm);
        prep_aux<<<NB_BORDER + NB_W, 256, 0, stream>>>(w1, w2, w1bf, w2bf, xpm);
        const int grid = Mn * (Bn * 1024 / NP);   // 16384
        nca_mfma_pm<<<grid, NT, 0, stream>>>(xpm, w1bf, b1, w2bf, b2, out);
    } else {
        const int grid = Mn * (Bn * 1024 / 128); // 8192
        nca_mfma_f32src<<<grid, NT, 0, stream>>>(x, w1, b1, w2, b2, out);
    }
}

// Round 14
// 159.859 us; speedup vs baseline: 1.9101x; 1.9101x over previous
//
#include <hip/hip_runtime.h>
#include <hip/hip_bf16.h>

// ParallelNCA on MFMA: 64 grouped MLPs (144->128->16) over 3x3 perception.
// Round 14: per-block 16-tile pipeline (NP=64), double-buffered LDS, gather
// via global_load_lds_dwordx4 (18 async 1KB loads/tile, zero VALU), weights
// in registers amortized over 16 tiles. launch_bounds(256,4) — r13's (,8)
// capped unified VGPR+AGPR at 64 and spilled catastrophically.

typedef __attribute__((ext_vector_type(8))) short short8;   // 8 bf16 frag
typedef __attribute__((ext_vector_type(4))) float f32x4;    // MFMA acc

constexpr int Bn  = 16;
constexpr int Mn  = 64;
constexpr int Cn  = 16;
constexpr int Hd  = 128;
constexpr int K9  = 144;
constexpr int MCn = 1024;
constexpr int NP  = 64;           // pixels per tile (2 image rows)
constexpr int CHUNKS = 18;        // 144 ch = 18 x 8ch(16B) chunks
constexpr int BUFB = CHUNKS * NP * 16;  // 18432 B per Pt buffer
constexpr int HT_STRIDE = 272;    // bytes/pixel row of Ht (17 16B slots, odd)
constexpr int NT  = 256;
constexpr int TILES = 16;         // tiles per block (full image per (m,b))

// pixel-major padded bf16 x: [b][h' 0..33][w' 0..33][mc 0..1023]
constexpr size_t XPM_SLABS = 34 * 34;
constexpr size_t XPM_B     = XPM_SLABS * MCn;               // ushorts per b
constexpr size_t XPM_BYTES = (size_t)Bn * XPM_B * 2;        // 37,879,808
constexpr size_t W1_ELEMS  = (size_t)Mn * Hd * K9;
constexpr size_t W2_ELEMS  = (size_t)Mn * Cn * Hd;
constexpr size_t WS_NEED   = XPM_BYTES + 2 * (W1_ELEMS + W2_ELEMS);

constexpr int NB_BORDER = Bn * 132;
constexpr int NB_W      = (int)((W1_ELEMS + W2_ELEMS) / 4 / 256);

__device__ __forceinline__ ushort f2bf(float f) {
    return __bfloat16_as_ushort(__float2bfloat16(f));
}
__device__ __forceinline__ float bf2f(ushort u) {
    union { uint i; float f; } v; v.i = (uint)u << 16; return v.f;
}

// ---------------------------------------------------------------------------
// prep: x [b][mc][32][32] f32 -> xpm [b][h+1][w+1][mc] bf16 (interior only)
// ---------------------------------------------------------------------------
__global__ __launch_bounds__(256)
void prep_xpm(const float* __restrict__ x, ushort* __restrict__ xpm)
{
    const int bid = blockIdx.x;
    const int b  = bid >> 7;
    const int h  = (bid >> 2) & 31;
    const int ck = bid & 3;
    const int tid = threadIdx.x;

    __shared__ ushort T[256][36];

    const int mc = ck * 256 + tid;
    const float* src = x + (((size_t)b * MCn + mc) * 32 + h) * 32;
    #pragma unroll
    for (int j = 0; j < 8; ++j) {
        const float4 f = *(const float4*)(src + 4 * j);
        uint2 pk;
        pk.x = (uint)f2bf(f.x) | ((uint)f2bf(f.y) << 16);
        pk.y = (uint)f2bf(f.z) | ((uint)f2bf(f.w) << 16);
        *(uint2*)&T[tid][4 * j] = pk;
    }
    __syncthreads();

    ushort* const dstb = xpm + (size_t)b * XPM_B + ((size_t)(h + 1) * 34) * MCn
                       + ck * 256;
    #pragma unroll
    for (int rep = 0; rep < 4; ++rep) {
        const int q8 = tid & 31;
        const int w  = (tid >> 5) + 8 * rep;
        ushort tmp[8];
        #pragma unroll
        for (int k2 = 0; k2 < 8; ++k2) tmp[k2] = T[8 * q8 + k2][w];
        uint4 v;
        v.x = (uint)tmp[0] | ((uint)tmp[1] << 16);
        v.y = (uint)tmp[2] | ((uint)tmp[3] << 16);
        v.z = (uint)tmp[4] | ((uint)tmp[5] << 16);
        v.w = (uint)tmp[6] | ((uint)tmp[7] << 16);
        *(uint4*)(dstb + (size_t)(w + 1) * MCn + 8 * q8) = v;
    }
}

// aux: border zero-fill + weight cvt
__global__ __launch_bounds__(256)
void prep_aux(const float* __restrict__ w1, const float* __restrict__ w2,
              ushort* __restrict__ w1bf, ushort* __restrict__ w2bf,
              ushort* __restrict__ xpm)
{
    const int bid = blockIdx.x;
    const int tid = threadIdx.x;
    if (bid < NB_BORDER) {
        const int b   = bid / 132;
        const int pos = bid % 132;
        int hh, ww;
        if      (pos < 34)  { hh = 0;              ww = pos;        }
        else if (pos < 68)  { hh = 33;             ww = pos - 34;   }
        else if (pos < 100) { hh = pos - 68 + 1;   ww = 0;          }
        else                { hh = pos - 100 + 1;  ww = 33;         }
        ushort* dst = xpm + (size_t)b * XPM_B + ((size_t)hh * 34 + ww) * MCn
                    + tid * 4;
        *(uint2*)dst = (uint2){0, 0};
    } else {
        const size_t i = ((size_t)(bid - NB_BORDER) * 256 + tid) * 4;
        const float* src; ushort* dst; size_t e;
        if (i < W1_ELEMS) { src = w1; dst = w1bf; e = i; }
        else              { src = w2; dst = w2bf; e = i - W1_ELEMS; }
        const float4 f = *(const float4*)(src + e);
        uint2 pk;
        pk.x = (uint)f2bf(f.x) | ((uint)f2bf(f.y) << 16);
        pk.y = (uint)f2bf(f.z) | ((uint)f2bf(f.w) << 16);
        *(uint2*)(dst + e) = pk;
    }
}

// ---------------------------------------------------------------------------
// main kernel: block = (m, batch); 16 tiles of 64 px, double-buffered Pt,
// async gather via global_load_lds (dest = uniform base + lane*16).
// Pt layout: [chunk 0..17][pixel 0..63][16B]  (chunk c = channels 8c..8c+8)
// ---------------------------------------------------------------------------
__global__ __launch_bounds__(NT, 4)
void nca_pipe(const ushort* __restrict__ xpm,
              const ushort* __restrict__ w1bf, const float* __restrict__ b1,
              const ushort* __restrict__ w2bf, const float* __restrict__ b2,
              float* __restrict__ out)
{
    __shared__ __align__(16) char U[2 * BUFB];   // 36864 B

    const int tid  = threadIdx.x;
    const int lane = tid & 63;
    const int wid  = tid >> 6;      // wave 0..3
    const int lr   = lane & 15;
    const int lk   = lane >> 4;

    // block -> (m, batch): bid = j*8+xcd; j -> (m = j&63, sethi = j>>6).
    // batch = sethi*8 + xcd  (per-XCD: all 64 m -> 2.5MB weights fit L2).
    const int bid   = blockIdx.x;
    const int xcd   = bid & 7;
    const int j     = bid >> 3;          // 0..127
    const int m     = j & 63;
    const int sethi = j >> 6;            // 0..1
    const int bb    = sethi * 8 + xcd;   // batch 0..15

    const ushort* const xpb = xpm + (size_t)bb * XPM_B;

    // ---------- weights (held in regs for all 16 tiles) ----------
    short8 a1[2][5];
    #pragma unroll
    for (int rt = 0; rt < 2; ++rt) {
        const int row = wid * 32 + rt * 16 + lr;
        const ushort* wr = w1bf + (m * Hd + row) * K9;
        #pragma unroll
        for (int ks = 0; ks < 5; ++ks) {
            const int k0 = ks * 32 + lk * 8;
            a1[rt][ks] = (k0 < K9) ? *(const short8*)(wr + k0)
                                   : (short8){0,0,0,0,0,0,0,0};
        }
    }
    short8 a2[4];
    #pragma unroll
    for (int ks = 0; ks < 4; ++ks)
        a2[ks] = *(const short8*)(w2bf + (m * Cn + lr) * Hd + ks * 32 + lk * 8);

    // ---------- per-chunk gather tables (wave wid owns chunks wid+4i) ----------
    // src(ushort) = r0*34816 + cb[i] + laneoff;  cb = ((dr+1)*34 + dc+1)*1024 + mc
    const unsigned long long TAB = 0xA62918405ull;   // (dr+1)|((dc+1)<<2)
    int cb[5];
    #pragma unroll
    for (int i = 0; i < 5; ++i) {
        const int c = wid + 4 * i;
        const int cc = (c < CHUNKS) ? c : 0;
        const int ch = m * K9 + cc * 8;
        const int s  = ch >> 10;
        const int mc = ch & 1023;
        const uint nib = (uint)(TAB >> (4 * s)) & 15u;
        const int dr = (int)(nib & 3u) - 1;
        const int dc = (int)(nib >> 2) - 1;
        cb[i] = ((dr + 1) * 34 + (dc + 1)) * 1024 + mc;
    }
    const int laneoff = ((lane >> 5) * 34 + (lane & 31)) * 1024;   // ushorts

    // stage tile t into buffer buf (18 async 1KB loads, 4-5 per wave)
    auto STAGE = [&](int t, char* buf) {
        const ushort* srcb = xpb + (size_t)(t * 2) * 34816 + laneoff;
        #pragma unroll
        for (int i = 0; i < 5; ++i) {
            const int c = wid + 4 * i;
            if (c < CHUNKS) {
                __builtin_amdgcn_global_load_lds(
                    (const __attribute__((address_space(1))) void*)(srcb + cb[i]),
                    (__attribute__((address_space(3))) void*)(buf + c * 1024),
                    16, 0, 0);
            }
        }
    };

    // prologue: tile 0 into buf 0
    STAGE(0, U);
    asm volatile("s_waitcnt vmcnt(0)" ::: "memory");
    __syncthreads();

    #pragma unroll 1
    for (int t = 0; t < TILES; ++t) {
        char* const A = U + (t & 1) * BUFB;
        char* const B = U + ((t + 1) & 1) * BUFB;
        if (t + 1 < TILES) STAGE(t + 1, B);      // async, lands during compute

        // ---------- GEMM1: hdn = w1 @ P, 128x64x144 ----------
        f32x4 acc[2][4];
        #pragma unroll
        for (int i = 0; i < 2; ++i)
            #pragma unroll
            for (int jj = 0; jj < 4; ++jj) acc[i][jj] = (f32x4){0.f, 0.f, 0.f, 0.f};

        #pragma unroll
        for (int ct = 0; ct < 4; ++ct) {
            const char* pb = A + (ct * 16 + lr) * 16;
            short8 bfrag[5];
            #pragma unroll
            for (int ks = 0; ks < 4; ++ks)
                bfrag[ks] = *(const short8*)(pb + (ks * 4 + lk) * 1024);
            bfrag[4] = (short8){0,0,0,0,0,0,0,0};
            if (lk < 2)                            // chunks 16,17 = ch 128..144
                bfrag[4] = *(const short8*)(pb + (16 + lk) * 1024);
            #pragma unroll
            for (int ks = 0; ks < 5; ++ks) {
                acc[0][ct] = __builtin_amdgcn_mfma_f32_16x16x32_bf16(a1[0][ks], bfrag[ks], acc[0][ct], 0, 0, 0);
                acc[1][ct] = __builtin_amdgcn_mfma_f32_16x16x32_bf16(a1[1][ks], bfrag[ks], acc[1][ct], 0, 0, 0);
            }
        }
        __syncthreads();   // A(Pt) reads done -> reuse A as Ht

        // ---------- bias+relu -> Ht[p][hd] bf16 (into A) ----------
        #pragma unroll
        for (int rt = 0; rt < 2; ++rt) {
            const int hd0 = wid * 32 + rt * 16 + lk * 4;   // C/D row=(lane>>4)*4+reg
            const float4 bs = *(const float4*)(b1 + m * Hd + hd0);
            #pragma unroll
            for (int ct = 0; ct < 4; ++ct) {
                const int p = ct * 16 + lr;                // C/D col = lane&15
                const f32x4 v = acc[rt][ct];
                uint2 pk;
                pk.x = (uint)f2bf(fmaxf(v[0] + bs.x, 0.f)) |
                       ((uint)f2bf(fmaxf(v[1] + bs.y, 0.f)) << 16);
                pk.y = (uint)f2bf(fmaxf(v[2] + bs.z, 0.f)) |
                       ((uint)f2bf(fmaxf(v[3] + bs.w, 0.f)) << 16);
                *(uint2*)(A + p * HT_STRIDE + hd0 * 2) = pk;
            }
        }
        __syncthreads();

        // ---------- GEMM2: dx = w2 @ hdn, 16x64x128 ----------
        f32x4 acc2;
        {
            const char* base = A + (wid * 16 + lr) * HT_STRIDE + lk * 16;
            short8 bbf[4];
            #pragma unroll
            for (int ks = 0; ks < 4; ++ks)
                bbf[ks] = *(const short8*)(base + ks * 64);
            f32x4 a = (f32x4){0.f, 0.f, 0.f, 0.f};
            #pragma unroll
            for (int ks = 0; ks < 4; ++ks)
                a = __builtin_amdgcn_mfma_f32_16x16x32_bf16(a2[ks], bbf[ks], a, 0, 0, 0);
            acc2 = a;
        }
        __syncthreads();   // Ht reads done -> reuse A as dxT

        // ---------- epilogue: residual + bias -> dxT(A) -> 256B out writes ----
        const int p0 = t * NP;
        {
            const float4 b2v = *(const float4*)(b2 + m * Cn + lk * 4);
            float (*dxT)[NP + 4] = (float(*)[NP + 4])A;
            const float bsv[4] = {b2v.x, b2v.y, b2v.z, b2v.w};
            const int px = wid * 16 + lr;
            const int gp = p0 + px;
            const int h  = gp >> 5, w = gp & 31;
            const ushort* res = xpb + ((h + 1) * 34 + (w + 1)) * MCn + m * Cn + lk * 4;
            #pragma unroll
            for (int rr2 = 0; rr2 < 4; ++rr2)
                dxT[lk * 4 + rr2][px] = acc2[rr2] + bsv[rr2] + bf2f(res[rr2]);
        }
        __syncthreads();
        {
            float (*dxT)[NP + 4] = (float(*)[NP + 4])A;
            const int c = tid >> 4, iq = tid & 15;
            const int px0 = 4 * iq;
            const float4 d0 = *(const float4*)&dxT[c][px0];
            const size_t idx = ((size_t)(bb * MCn + m * Cn + c)) * 1024 + p0 + px0;
            *(float4*)(out + idx) = d0;
        }

        // next tile's Pt must be fully landed before its ds_reads
        asm volatile("s_waitcnt vmcnt(0)" ::: "memory");
        __syncthreads();
    }
}

// ---------------------------------------------------------------------------
// fallback (f32-direct, round 6): used when ws_size < WS_NEED
// ---------------------------------------------------------------------------
constexpr int PT_STRIDE_FB = 304;
__global__ __launch_bounds__(NT, 4)
void nca_mfma_f32src(const float* __restrict__ x,  const float* __restrict__ w1,
                     const float* __restrict__ b1, const float* __restrict__ w2,
                     const float* __restrict__ b2, float* __restrict__ out)
{
    __shared__ __align__(16) char U[128 * PT_STRIDE_FB + 16];
    char* const PtL = U;
    char* const HtL = U;

    const int tid  = threadIdx.x;
    const int lane = tid & 63;
    const int wid  = tid >> 6;
    const int lr   = lane & 15;
    const int lk   = lane >> 4;

    const int bid = blockIdx.x;
    const int xcd = bid & 7;
    const int jb  = bid >> 3;
    const int m   = jb & 63;
    const int g   = (jb >> 6) * 8 + xcd;
    const int b   = g >> 3;
    const int p0  = (g & 7) * 128;

    if (tid <= 128) {
        char* z = PtL + tid * PT_STRIDE_FB + (tid < 128 ? 288 : 0);
        *(int4*)z = (int4){0, 0, 0, 0};
    }

    short8 a1[2][5];
    #pragma unroll
    for (int rt = 0; rt < 2; ++rt) {
        const int row = wid * 32 + rt * 16 + lr;
        const float* wr = w1 + (m * Hd + row) * K9;
        #pragma unroll
        for (int ks = 0; ks < 5; ++ks) {
            const int k0 = ks * 32 + lk * 8;
            short8 t;
            if (k0 < K9) {
                const float4 f0 = *(const float4*)(wr + k0);
                const float4 f1 = *(const float4*)(wr + k0 + 4);
                t[0] = (short)f2bf(f0.x); t[1] = (short)f2bf(f0.y);
                t[2] = (short)f2bf(f0.z); t[3] = (short)f2bf(f0.w);
                t[4] = (short)f2bf(f1.x); t[5] = (short)f2bf(f1.y);
                t[6] = (short)f2bf(f1.z); t[7] = (short)f2bf(f1.w);
            } else t = (short8){0,0,0,0,0,0,0,0};
            a1[rt][ks] = t;
        }
    }
    short8 a2[4];
    #pragma unroll
    for (int ks = 0; ks < 4; ++ks) {
        const float* wr = w2 + (m * Cn + lr) * Hd + ks * 32 + lk * 8;
        const float4 f0 = *(const float4*)(wr);
        const float4 f1 = *(const float4*)(wr + 4);
        short8 t;
        t[0] = (short)f2bf(f0.x); t[1] = (short)f2bf(f0.y);
        t[2] = (short)f2bf(f0.z); t[3] = (short)f2bf(f0.w);
        t[4] = (short)f2bf(f1.x); t[5] = (short)f2bf(f1.y);
        t[6] = (short)f2bf(f1.z); t[7] = (short)f2bf(f1.w);
        a2[ks] = t;
    }
    {
        const int s     = tid & 7;
        const int kpl   = (tid >> 3) & 7;
        const int r     = tid >> 6;
        const int rbase = (g & 7) * 4 + r;
        const float* xb = x + (size_t)b * (MCn * 1024);
        const unsigned long long TAB = 0xA62918405ull;
        #pragma unroll
        for (int it = 0; it < 9; ++it) {
            const int kp = it * 8 + kpl;
            float4 hv[2];
            #pragma unroll
            for (int half = 0; half < 2; ++half) {
                const int ch = m * K9 + kp * 2 + half;
                const int sh = ch >> 10;
                const int mc = ch & 1023;
                const uint nib = (uint)(TAB >> (4 * sh)) & 15u;
                const int dr = (int)(nib & 3u) - 1;
                const int dc = (int)(nib >> 2) - 1;
                const int row = rbase + dr;
                const int wb  = 4 * s + dc;
                const int wc  = min(max(wb, 0), 28);
                float4 f = {0.f, 0.f, 0.f, 0.f};
                if ((unsigned)row < 32u)
                    f = *(const float4*)(xb + (mc * 32 + row) * 32 + wc);
                if (wb < 0)       { f.w = f.z; f.z = f.y; f.y = f.x; f.x = 0.f; }
                else if (wb > 28) { f.x = f.y; f.y = f.z; f.z = f.w; f.w = 0.f; }
                hv[half] = f;
            }
            char* dst = PtL + (r * 32 + 4 * s) * PT_STRIDE_FB + kp * 4;
            *(uint*)(dst)                    = (uint)f2bf(hv[0].x) | ((uint)f2bf(hv[1].x) << 16);
            *(uint*)(dst + PT_STRIDE_FB)     = (uint)f2bf(hv[0].y) | ((uint)f2bf(hv[1].y) << 16);
            *(uint*)(dst + 2 * PT_STRIDE_FB) = (uint)f2bf(hv[0].z) | ((uint)f2bf(hv[1].z) << 16);
            *(uint*)(dst + 3 * PT_STRIDE_FB) = (uint)f2bf(hv[0].w) | ((uint)f2bf(hv[1].w) << 16);
        }
    }
    __syncthreads();

    f32x4 acc[2][8];
    #pragma unroll
    for (int i = 0; i < 2; ++i)
        #pragma unroll
        for (int jj = 0; jj < 8; ++jj) acc[i][jj] = (f32x4){0.f, 0.f, 0.f, 0.f};
    #pragma unroll
    for (int ct = 0; ct < 8; ++ct) {
        const int p = ct * 16 + lr;
        const char* base = PtL + p * PT_STRIDE_FB + lk * 16;
        short8 bfrag[5];
        #pragma unroll
        for (int ks = 0; ks < 5; ++ks)
            bfrag[ks] = *(const short8*)(base + ks * 64);
        #pragma unroll
        for (int ks = 0; ks < 5; ++ks) {
            acc[0][ct] = __builtin_amdgcn_mfma_f32_16x16x32_bf16(a1[0][ks], bfrag[ks], acc[0][ct], 0, 0, 0);
            acc[1][ct] = __builtin_amdgcn_mfma_f32_16x16x32_bf16(a1[1][ks], bfrag[ks], acc[1][ct], 0, 0, 0);
        }
    }
    __syncthreads();
    #pragma unroll
    for (int rt = 0; rt < 2; ++rt) {
        const int hd0 = wid * 32 + rt * 16 + lk * 4;
        const float4 bs = *(const float4*)(b1 + m * Hd + hd0);
        #pragma unroll
        for (int ct = 0; ct < 8; ++ct) {
            const int p = ct * 16 + lr;
            const f32x4 v = acc[rt][ct];
            uint2 pk;
            pk.x = (uint)f2bf(fmaxf(v[0] + bs.x, 0.f)) |
                   ((uint)f2bf(fmaxf(v[1] + bs.y, 0.f)) << 16);
            pk.y = (uint)f2bf(fmaxf(v[2] + bs.z, 0.f)) |
                   ((uint)f2bf(fmaxf(v[3] + bs.w, 0.f)) << 16);
            *(uint2*)(HtL + p * HT_STRIDE + hd0 * 2) = pk;
        }
    }
    __syncthreads();
    f32x4 acc2[2];
    #pragma unroll
    for (int jj = 0; jj < 2; ++jj) {
        const int ct = wid * 2 + jj;
        const int p  = ct * 16 + lr;
        const char* base = HtL + p * HT_STRIDE + lk * 16;
        short8 bbf[4];
        #pragma unroll
        for (int ks = 0; ks < 4; ++ks)
            bbf[ks] = *(const short8*)(base + ks * 64);
        f32x4 a = (f32x4){0.f, 0.f, 0.f, 0.f};
        #pragma unroll
        for (int ks = 0; ks < 4; ++ks)
            a = __builtin_amdgcn_mfma_f32_16x16x32_bf16(a2[ks], bbf[ks], a, 0, 0, 0);
        acc2[jj] = a;
    }
    const float4 b2v = *(const float4*)(b2 + m * Cn + lk * 4);
    const float bsv[4] = {b2v.x, b2v.y, b2v.z, b2v.w};
    #pragma unroll
    for (int jj = 0; jj < 2; ++jj) {
        const int ct = wid * 2 + jj;
        const int gp = p0 + ct * 16 + lr;
        #pragma unroll
        for (int r = 0; r < 4; ++r) {
            const int c   = lk * 4 + r;
            const size_t idx = ((size_t)(b * MCn + m * Cn + c)) * 1024 + gp;
            out[idx] = x[idx] + acc2[jj][r] + bsv[r];
        }
    }
}

extern "C" void kernel_launch(void* const* d_in, const int* in_sizes, int n_in,
                              void* d_out, int out_size, void* d_ws, size_t ws_size,
                              hipStream_t stream)
{
    const float* x  = (const float*)d_in[0];
    const float* w1 = (const float*)d_in[1];
    const float* b1 = (const float*)d_in[2];
    const float* w2 = (const float*)d_in[3];
    const float* b2 = (const float*)d_in[4];
    float* out = (float*)d_out;

    if (ws_size >= WS_NEED) {
        ushort* xpm  = (ushort*)d_ws;
        ushort* w1bf = (ushort*)((char*)d_ws + XPM_BYTES);
        ushort* w2bf = w1bf + W1_ELEMS;
        prep_xpm<<<Bn * 32 * 4, 256, 0, stream>>>(x, xpm);
        prep_aux<<<NB_BORDER + NB_W, 256, 0, stream>>>(w1, w2, w1bf, w2bf, xpm);
        nca_pipe<<<Mn * Bn, NT, 0, stream>>>(xpm, w1bf, b1, w2bf, b2, out);  // 1024
    } else {
        nca_mfma_f32src<<<Mn * (Bn * 1024 / 128), NT, 0, stream>>>(x, w1, b1, w2, b2, out);
    }
}

// Round 16
// 155.654 us; speedup vs baseline: 1.9617x; 1.0270x over previous
//
#include <hip/hip_runtime.h>
#include <hip/hip_bf16.h>

// ParallelNCA on MFMA: 64 grouped MLPs (144->128->16) over 3x3 perception.
// Round 15 = r14 pipeline with locality/grid fix:
//  - block = (m, b, quarter): TILES=4, grid 4096 (16 queued/CU).
//  - per-XCD order (mlo,bhi,mch,q): working set 0.7MB slab + 1.26MB weights
//    < 4MB L2 (r14 had 2 batches + all weights = 7.2MB -> FETCH 250MB).
//  - GEMM2 operand-swapped: D[px][c] -> direct float4 epilogue, no dxT LDS,
//    5 -> 3 barriers per tile.

typedef __attribute__((ext_vector_type(8))) short short8;   // 8 bf16 frag
typedef __attribute__((ext_vector_type(4))) float f32x4;    // MFMA acc

constexpr int Bn  = 16;
constexpr int Mn  = 64;
constexpr int Cn  = 16;
constexpr int Hd  = 128;
constexpr int K9  = 144;
constexpr int MCn = 1024;
constexpr int NP  = 64;           // pixels per tile (2 image rows)
constexpr int CHUNKS = 18;        // 144 ch = 18 x 8ch(16B) chunks
constexpr int BUFB = CHUNKS * NP * 16;  // 18432 B per Pt buffer
constexpr int HT_STRIDE = 272;    // bytes/pixel row of Ht (17 16B slots, odd)
constexpr int NT  = 256;
constexpr int TILES = 4;          // tiles per block (quarter image)

// pixel-major padded bf16 x: [b][h' 0..33][w' 0..33][mc 0..1023]
constexpr size_t XPM_SLABS = 34 * 34;
constexpr size_t XPM_B     = XPM_SLABS * MCn;               // ushorts per b
constexpr size_t XPM_BYTES = (size_t)Bn * XPM_B * 2;        // 37,879,808
constexpr size_t W1_ELEMS  = (size_t)Mn * Hd * K9;
constexpr size_t W2_ELEMS  = (size_t)Mn * Cn * Hd;
constexpr size_t WS_NEED   = XPM_BYTES + 2 * (W1_ELEMS + W2_ELEMS);

constexpr int NB_BORDER = Bn * 132;
constexpr int NB_W      = (int)((W1_ELEMS + W2_ELEMS) / 4 / 256);

__device__ __forceinline__ ushort f2bf(float f) {
    return __bfloat16_as_ushort(__float2bfloat16(f));
}
__device__ __forceinline__ float bf2f(ushort u) {
    union { uint i; float f; } v; v.i = (uint)u << 16; return v.f;
}

// ---------------------------------------------------------------------------
// prep: x [b][mc][32][32] f32 -> xpm [b][h+1][w+1][mc] bf16 (interior only)
// ---------------------------------------------------------------------------
__global__ __launch_bounds__(256)
void prep_xpm(const float* __restrict__ x, ushort* __restrict__ xpm)
{
    const int bid = blockIdx.x;
    const int b  = bid >> 7;
    const int h  = (bid >> 2) & 31;
    const int ck = bid & 3;
    const int tid = threadIdx.x;

    __shared__ ushort T[256][36];

    const int mc = ck * 256 + tid;
    const float* src = x + (((size_t)b * MCn + mc) * 32 + h) * 32;
    #pragma unroll
    for (int j = 0; j < 8; ++j) {
        const float4 f = *(const float4*)(src + 4 * j);
        uint2 pk;
        pk.x = (uint)f2bf(f.x) | ((uint)f2bf(f.y) << 16);
        pk.y = (uint)f2bf(f.z) | ((uint)f2bf(f.w) << 16);
        *(uint2*)&T[tid][4 * j] = pk;
    }
    __syncthreads();

    ushort* const dstb = xpm + (size_t)b * XPM_B + ((size_t)(h + 1) * 34) * MCn
                       + ck * 256;
    #pragma unroll
    for (int rep = 0; rep < 4; ++rep) {
        const int q8 = tid & 31;
        const int w  = (tid >> 5) + 8 * rep;
        ushort tmp[8];
        #pragma unroll
        for (int k2 = 0; k2 < 8; ++k2) tmp[k2] = T[8 * q8 + k2][w];
        uint4 v;
        v.x = (uint)tmp[0] | ((uint)tmp[1] << 16);
        v.y = (uint)tmp[2] | ((uint)tmp[3] << 16);
        v.z = (uint)tmp[4] | ((uint)tmp[5] << 16);
        v.w = (uint)tmp[6] | ((uint)tmp[7] << 16);
        *(uint4*)(dstb + (size_t)(w + 1) * MCn + 8 * q8) = v;
    }
}

// aux: border zero-fill + weight cvt
__global__ __launch_bounds__(256)
void prep_aux(const float* __restrict__ w1, const float* __restrict__ w2,
              ushort* __restrict__ w1bf, ushort* __restrict__ w2bf,
              ushort* __restrict__ xpm)
{
    const int bid = blockIdx.x;
    const int tid = threadIdx.x;
    if (bid < NB_BORDER) {
        const int b   = bid / 132;
        const int pos = bid % 132;
        int hh, ww;
        if      (pos < 34)  { hh = 0;              ww = pos;        }
        else if (pos < 68)  { hh = 33;             ww = pos - 34;   }
        else if (pos < 100) { hh = pos - 68 + 1;   ww = 0;          }
        else                { hh = pos - 100 + 1;  ww = 33;         }
        ushort* dst = xpm + (size_t)b * XPM_B + ((size_t)hh * 34 + ww) * MCn
                    + tid * 4;
        *(uint2*)dst = (uint2){0, 0};
    } else {
        const size_t i = ((size_t)(bid - NB_BORDER) * 256 + tid) * 4;
        const float* src; ushort* dst; size_t e;
        if (i < W1_ELEMS) { src = w1; dst = w1bf; e = i; }
        else              { src = w2; dst = w2bf; e = i - W1_ELEMS; }
        const float4 f = *(const float4*)(src + e);
        uint2 pk;
        pk.x = (uint)f2bf(f.x) | ((uint)f2bf(f.y) << 16);
        pk.y = (uint)f2bf(f.z) | ((uint)f2bf(f.w) << 16);
        *(uint2*)(dst + e) = pk;
    }
}

// ---------------------------------------------------------------------------
// main kernel: block = (m, batch, quarter); 4 tiles of 64 px, double-buffered
// Pt, async gather via global_load_lds. Pt layout: [chunk 0..17][pixel][16B].
// ---------------------------------------------------------------------------
__global__ __launch_bounds__(NT, 4)
void nca_pipe(const ushort* __restrict__ xpm,
              const ushort* __restrict__ w1bf, const float* __restrict__ b1,
              const ushort* __restrict__ w2bf, const float* __restrict__ b2,
              float* __restrict__ out)
{
    __shared__ __align__(16) char U[2 * BUFB];   // 36864 B

    const int tid  = threadIdx.x;
    const int lane = tid & 63;
    const int wid  = tid >> 6;      // wave 0..3
    const int lr   = lane & 15;
    const int lk   = lane >> 4;

    // decode: bid = j*8 + xcd; j = q*128 + mch*64 + bhi*32 + mlo
    const int bid = blockIdx.x;
    const int xcd = bid & 7;
    const int j   = bid >> 3;            // 0..511
    const int mlo = j & 31;
    const int bhi = (j >> 5) & 1;
    const int mch = (j >> 6) & 1;
    const int q   = j >> 7;              // 0..3
    const int m   = mch * 32 + mlo;
    const int bb  = bhi * 8 + xcd;       // batch 0..15 (pinned to one XCD)

    const ushort* const xpb = xpm + (size_t)bb * XPM_B;

    // ---------- weights (held in regs for 4 tiles) ----------
    short8 a1[2][5];
    #pragma unroll
    for (int rt = 0; rt < 2; ++rt) {
        const int row = wid * 32 + rt * 16 + lr;
        const ushort* wr = w1bf + (m * Hd + row) * K9;
        #pragma unroll
        for (int ks = 0; ks < 5; ++ks) {
            const int k0 = ks * 32 + lk * 8;
            a1[rt][ks] = (k0 < K9) ? *(const short8*)(wr + k0)
                                   : (short8){0,0,0,0,0,0,0,0};
        }
    }
    short8 a2[4];
    #pragma unroll
    for (int ks = 0; ks < 4; ++ks)
        a2[ks] = *(const short8*)(w2bf + (m * Cn + lr) * Hd + ks * 32 + lk * 8);

    // ---------- per-chunk gather tables (wave wid owns chunks wid+4i) ----------
    const unsigned long long TAB = 0xA62918405ull;   // (dr+1)|((dc+1)<<2)
    int cb[5];
    #pragma unroll
    for (int i = 0; i < 5; ++i) {
        const int c = wid + 4 * i;
        const int cc = (c < CHUNKS) ? c : 0;
        const int ch = m * K9 + cc * 8;
        const int s  = ch >> 10;
        const int mc = ch & 1023;
        const uint nib = (uint)(TAB >> (4 * s)) & 15u;
        const int dr = (int)(nib & 3u) - 1;
        const int dc = (int)(nib >> 2) - 1;
        cb[i] = ((dr + 1) * 34 + (dc + 1)) * 1024 + mc;
    }
    const int laneoff = ((lane >> 5) * 34 + (lane & 31)) * 1024;   // ushorts

    auto STAGE = [&](int t, char* buf) {
        const ushort* srcb = xpb + (size_t)(q * 8 + t * 2) * 34816 + laneoff;
        #pragma unroll
        for (int i = 0; i < 5; ++i) {
            const int c = wid + 4 * i;
            if (c < CHUNKS) {
                __builtin_amdgcn_global_load_lds(
                    (const __attribute__((address_space(1))) void*)(srcb + cb[i]),
                    (__attribute__((address_space(3))) void*)(buf + c * 1024),
                    16, 0, 0);
            }
        }
    };

    STAGE(0, U);
    asm volatile("s_waitcnt vmcnt(0)" ::: "memory");
    __syncthreads();

    #pragma unroll 1
    for (int t = 0; t < TILES; ++t) {
        char* const A = U + (t & 1) * BUFB;
        char* const B = U + ((t + 1) & 1) * BUFB;
        if (t + 1 < TILES) STAGE(t + 1, B);      // async, lands during compute

        // ---------- GEMM1: hdn = w1 @ P, 128x64x144 ----------
        f32x4 acc[2][4];
        #pragma unroll
        for (int i = 0; i < 2; ++i)
            #pragma unroll
            for (int jj = 0; jj < 4; ++jj) acc[i][jj] = (f32x4){0.f, 0.f, 0.f, 0.f};

        #pragma unroll
        for (int ct = 0; ct < 4; ++ct) {
            const char* pb = A + (ct * 16 + lr) * 16;
            short8 bfrag[5];
            #pragma unroll
            for (int ks = 0; ks < 4; ++ks)
                bfrag[ks] = *(const short8*)(pb + (ks * 4 + lk) * 1024);
            bfrag[4] = (short8){0,0,0,0,0,0,0,0};
            if (lk < 2)                            // chunks 16,17 = ch 128..144
                bfrag[4] = *(const short8*)(pb + (16 + lk) * 1024);
            #pragma unroll
            for (int ks = 0; ks < 5; ++ks) {
                acc[0][ct] = __builtin_amdgcn_mfma_f32_16x16x32_bf16(a1[0][ks], bfrag[ks], acc[0][ct], 0, 0, 0);
                acc[1][ct] = __builtin_amdgcn_mfma_f32_16x16x32_bf16(a1[1][ks], bfrag[ks], acc[1][ct], 0, 0, 0);
            }
        }
        __syncthreads();   // A(Pt) reads done -> reuse A as Ht

        // ---------- bias+relu -> Ht[p][hd] bf16 (into A) ----------
        #pragma unroll
        for (int rt = 0; rt < 2; ++rt) {
            const int hd0 = wid * 32 + rt * 16 + lk * 4;   // C/D row=(lane>>4)*4+reg
            const float4 bs = *(const float4*)(b1 + m * Hd + hd0);
            #pragma unroll
            for (int ct = 0; ct < 4; ++ct) {
                const int p = ct * 16 + lr;                // C/D col = lane&15
                const f32x4 v = acc[rt][ct];
                uint2 pk;
                pk.x = (uint)f2bf(fmaxf(v[0] + bs.x, 0.f)) |
                       ((uint)f2bf(fmaxf(v[1] + bs.y, 0.f)) << 16);
                pk.y = (uint)f2bf(fmaxf(v[2] + bs.z, 0.f)) |
                       ((uint)f2bf(fmaxf(v[3] + bs.w, 0.f)) << 16);
                *(uint2*)(A + p * HT_STRIDE + hd0 * 2) = pk;
            }
        }
        __syncthreads();

        // ---------- GEMM2 (operand-swapped): D[px][c] = Ht · w2^T ----------
        // A-op = Ht frags (row=px=wid*16+lr), B-op = a2 (col=c=lr).
        // D: col=lane&15=c, row=(lane>>4)*4+reg = px-within-16.
        f32x4 acc2;
        {
            const char* base = A + (wid * 16 + lr) * HT_STRIDE + lk * 16;
            short8 hf[4];
            #pragma unroll
            for (int ks = 0; ks < 4; ++ks)
                hf[ks] = *(const short8*)(base + ks * 64);
            f32x4 a = (f32x4){0.f, 0.f, 0.f, 0.f};
            #pragma unroll
            for (int ks = 0; ks < 4; ++ks)
                a = __builtin_amdgcn_mfma_f32_16x16x32_bf16(hf[ks], a2[ks], a, 0, 0, 0);
            acc2 = a;
        }

        // ---------- epilogue: direct per-lane store (c=lr, 4 consecutive px) ---
        {
            const int p0  = q * 256 + t * NP;
            const int c   = lr;
            const int gp0 = p0 + wid * 16 + lk * 4;
            const int h   = gp0 >> 5, w0 = gp0 & 31;
            const float bsv = b2[m * Cn + c];
            const ushort* res = xpb + ((h + 1) * 34 + (w0 + 1)) * MCn + m * Cn + c;
            float4 o;
            o.x = acc2[0] + bsv + bf2f(res[0]);
            o.y = acc2[1] + bsv + bf2f(res[MCn]);
            o.z = acc2[2] + bsv + bf2f(res[2 * MCn]);
            o.w = acc2[3] + bsv + bf2f(res[3 * MCn]);
            const size_t idx = ((size_t)(bb * MCn + m * Cn + c)) * 1024 + gp0;
            *(float4*)(out + idx) = o;
        }

        // next tile's Pt landed + all Ht reads done before STAGE overwrites A
        asm volatile("s_waitcnt vmcnt(0)" ::: "memory");
        __syncthreads();
    }
}

// ---------------------------------------------------------------------------
// fallback (f32-direct, round 6): used when ws_size < WS_NEED
// ---------------------------------------------------------------------------
constexpr int PT_STRIDE_FB = 304;
__global__ __launch_bounds__(NT, 4)
void nca_mfma_f32src(const float* __restrict__ x,  const float* __restrict__ w1,
                     const float* __restrict__ b1, const float* __restrict__ w2,
                     const float* __restrict__ b2, float* __restrict__ out)
{
    __shared__ __align__(16) char U[128 * PT_STRIDE_FB + 16];
    char* const PtL = U;
    char* const HtL = U;

    const int tid  = threadIdx.x;
    const int lane = tid & 63;
    const int wid  = tid >> 6;
    const int lr   = lane & 15;
    const int lk   = lane >> 4;

    const int bid = blockIdx.x;
    const int xcd = bid & 7;
    const int jb  = bid >> 3;
    const int m   = jb & 63;
    const int g   = (jb >> 6) * 8 + xcd;
    const int b   = g >> 3;
    const int p0  = (g & 7) * 128;

    if (tid <= 128) {
        char* z = PtL + tid * PT_STRIDE_FB + (tid < 128 ? 288 : 0);
        *(int4*)z = (int4){0, 0, 0, 0};
    }

    short8 a1[2][5];
    #pragma unroll
    for (int rt = 0; rt < 2; ++rt) {
        const int row = wid * 32 + rt * 16 + lr;
        const float* wr = w1 + (m * Hd + row) * K9;
        #pragma unroll
        for (int ks = 0; ks < 5; ++ks) {
            const int k0 = ks * 32 + lk * 8;
            short8 t;
            if (k0 < K9) {
                const float4 f0 = *(const float4*)(wr + k0);
                const float4 f1 = *(const float4*)(wr + k0 + 4);
                t[0] = (short)f2bf(f0.x); t[1] = (short)f2bf(f0.y);
                t[2] = (short)f2bf(f0.z); t[3] = (short)f2bf(f0.w);
                t[4] = (short)f2bf(f1.x); t[5] = (short)f2bf(f1.y);
                t[6] = (short)f2bf(f1.z); t[7] = (short)f2bf(f1.w);
            } else t = (short8){0,0,0,0,0,0,0,0};
            a1[rt][ks] = t;
        }
    }
    short8 a2[4];
    #pragma unroll
    for (int ks = 0; ks < 4; ++ks) {
        const float* wr = w2 + (m * Cn + lr) * Hd + ks * 32 + lk * 8;
        const float4 f0 = *(const float4*)(wr);
        const float4 f1 = *(const float4*)(wr + 4);
        short8 t;
        t[0] = (short)f2bf(f0.x); t[1] = (short)f2bf(f0.y);
        t[2] = (short)f2bf(f0.z); t[3] = (short)f2bf(f0.w);
        t[4] = (short)f2bf(f1.x); t[5] = (short)f2bf(f1.y);
        t[6] = (short)f2bf(f1.z); t[7] = (short)f2bf(f1.w);
        a2[ks] = t;
    }
    {
        const int s     = tid & 7;
        const int kpl   = (tid >> 3) & 7;
        const int r     = tid >> 6;
        const int rbase = (g & 7) * 4 + r;
        const float* xb = x + (size_t)b * (MCn * 1024);
        const unsigned long long TAB = 0xA62918405ull;
        #pragma unroll
        for (int it = 0; it < 9; ++it) {
            const int kp = it * 8 + kpl;
            float4 hv[2];
            #pragma unroll
            for (int half = 0; half < 2; ++half) {
                const int ch = m * K9 + kp * 2 + half;
                const int sh = ch >> 10;
                const int mc = ch & 1023;
                const uint nib = (uint)(TAB >> (4 * sh)) & 15u;
                const int dr = (int)(nib & 3u) - 1;
                const int dc = (int)(nib >> 2) - 1;
                const int row = rbase + dr;
                const int wb  = 4 * s + dc;
                const int wc  = min(max(wb, 0), 28);
                float4 f = {0.f, 0.f, 0.f, 0.f};
                if ((unsigned)row < 32u)
                    f = *(const float4*)(xb + (mc * 32 + row) * 32 + wc);
                if (wb < 0)       { f.w = f.z; f.z = f.y; f.y = f.x; f.x = 0.f; }
                else if (wb > 28) { f.x = f.y; f.y = f.z; f.z = f.w; f.w = 0.f; }
                hv[half] = f;
            }
            char* dst = PtL + (r * 32 + 4 * s) * PT_STRIDE_FB + kp * 4;
            *(uint*)(dst)                    = (uint)f2bf(hv[0].x) | ((uint)f2bf(hv[1].x) << 16);
            *(uint*)(dst + PT_STRIDE_FB)     = (uint)f2bf(hv[0].y) | ((uint)f2bf(hv[1].y) << 16);
            *(uint*)(dst + 2 * PT_STRIDE_FB) = (uint)f2bf(hv[0].z) | ((uint)f2bf(hv[1].z) << 16);
            *(uint*)(dst + 3 * PT_STRIDE_FB) = (uint)f2bf(hv[0].w) | ((uint)f2bf(hv[1].w) << 16);
        }
    }
    __syncthreads();

    f32x4 acc[2][8];
    #pragma unroll
    for (int i = 0; i < 2; ++i)
        #pragma unroll
        for (int jj = 0; jj < 8; ++jj) acc[i][jj] = (f32x4){0.f, 0.f, 0.f, 0.f};
    #pragma unroll
    for (int ct = 0; ct < 8; ++ct) {
        const int p = ct * 16 + lr;
        const char* base = PtL + p * PT_STRIDE_FB + lk * 16;
        short8 bfrag[5];
        #pragma unroll
        for (int ks = 0; ks < 5; ++ks)
            bfrag[ks] = *(const short8*)(base + ks * 64);
        #pragma unroll
        for (int ks = 0; ks < 5; ++ks) {
            acc[0][ct] = __builtin_amdgcn_mfma_f32_16x16x32_bf16(a1[0][ks], bfrag[ks], acc[0][ct], 0, 0, 0);
            acc[1][ct] = __builtin_amdgcn_mfma_f32_16x16x32_bf16(a1[1][ks], bfrag[ks], acc[1][ct], 0, 0, 0);
        }
    }
    __syncthreads();
    #pragma unroll
    for (int rt = 0; rt < 2; ++rt) {
        const int hd0 = wid * 32 + rt * 16 + lk * 4;
        const float4 bs = *(const float4*)(b1 + m * Hd + hd0);
        #pragma unroll
        for (int ct = 0; ct < 8; ++ct) {
            const int p = ct * 16 + lr;
            const f32x4 v = acc[rt][ct];
            uint2 pk;
            pk.x = (uint)f2bf(fmaxf(v[0] + bs.x, 0.f)) |
                   ((uint)f2bf(fmaxf(v[1] + bs.y, 0.f)) << 16);
            pk.y = (uint)f2bf(fmaxf(v[2] + bs.z, 0.f)) |
                   ((uint)f2bf(fmaxf(v[3] + bs.w, 0.f)) << 16);
            *(uint2*)(HtL + p * HT_STRIDE + hd0 * 2) = pk;
        }
    }
    __syncthreads();
    f32x4 acc2[2];
    #pragma unroll
    for (int jj = 0; jj < 2; ++jj) {
        const int ct = wid * 2 + jj;
        const int p  = ct * 16 + lr;
        const char* base = HtL + p * HT_STRIDE + lk * 16;
        short8 bbf[4];
        #pragma unroll
        for (int ks = 0; ks < 4; ++ks)
            bbf[ks] = *(const short8*)(base + ks * 64);
        f32x4 a = (f32x4){0.f, 0.f, 0.f, 0.f};
        #pragma unroll
        for (int ks = 0; ks < 4; ++ks)
            a = __builtin_amdgcn_mfma_f32_16x16x32_bf16(a2[ks], bbf[ks], a, 0, 0, 0);
        acc2[jj] = a;
    }
    const float4 b2v = *(const float4*)(b2 + m * Cn + lk * 4);
    const float bsv[4] = {b2v.x, b2v.y, b2v.z, b2v.w};
    #pragma unroll
    for (int jj = 0; jj < 2; ++jj) {
        const int ct = wid * 2 + jj;
        const int gp = p0 + ct * 16 + lr;
        #pragma unroll
        for (int r = 0; r < 4; ++r) {
            const int c   = lk * 4 + r;
            const size_t idx = ((size_t)(b * MCn + m * Cn + c)) * 1024 + gp;
            out[idx] = x[idx] + acc2[jj][r] + bsv[r];
        }
    }
}

extern "C" void kernel_launch(void* const* d_in, const int* in_sizes, int n_in,
                              void* d_out, int out_size, void* d_ws, size_t ws_size,
                              hipStream_t stream)
{
    const float* x  = (const float*)d_in[0];
    const float* w1 = (const float*)d_in[1];
    const float* b1 = (const float*)d_in[2];
    const float* w2 = (const float*)d_in[3];
    const float* b2 = (const float*)d_in[4];
    float* out = (float*)d_out;

    if (ws_size >= WS_NEED) {
        ushort* xpm  = (ushort*)d_ws;
        ushort* w1bf = (ushort*)((char*)d_ws + XPM_BYTES);
        ushort* w2bf = w1bf + W1_ELEMS;
        prep_xpm<<<Bn * 32 * 4, 256, 0, stream>>>(x, xpm);
        prep_aux<<<NB_BORDER + NB_W, 256, 0, stream>>>(w1, w2, w1bf, w2bf, xpm);
        nca_pipe<<<Mn * Bn * TILES, NT, 0, stream>>>(xpm, w1bf, b1, w2bf, b2, out);  // 4096
    } else {
        nca_mfma_f32src<<<Mn * (Bn * 1024 / 128), NT, 0, stream>>>(x, w1, b1, w2, b2, out);
    }
}